// Round 11
// baseline (544.283 us; speedup 1.0000x reference)
//
#include <hip/hip_runtime.h>
#include <stdint.h>
#include <math.h>

typedef __attribute__((ext_vector_type(8))) short s16x8;
typedef __attribute__((ext_vector_type(4))) short s16x4;
typedef __attribute__((ext_vector_type(4))) float f32x4;
typedef __attribute__((ext_vector_type(16))) float f32x16;

#define NEGH (-1.0e30f)

__device__ __forceinline__ short f2bf(float f) {
  union { float f; unsigned int i; } c; c.f = f;
  unsigned int lsb = (c.i >> 16) & 1u;
  c.i += 0x7fffu + lsb;
  return (short)(c.i >> 16);
}
__device__ __forceinline__ float bf2f(short u) {
  union { unsigned int i; float f; } c;
  c.i = ((unsigned int)(unsigned short)u) << 16;
  return c.f;
}

// async global->LDS, 16B per lane. LDS dest must be wave-uniform base + lane*16.
#define GLOAD_LDS16(gp, lp)                                                  \
  __builtin_amdgcn_global_load_lds(                                          \
      (__attribute__((address_space(1))) void*)(void*)(gp),                  \
      (__attribute__((address_space(3))) void*)(lp), 16, 0, 0)

// ---------------------------------------------------------------------------
// fp32 -> bf16 conversion, 4 elements/thread. n must be divisible by 1024.
// ---------------------------------------------------------------------------
__global__ __launch_bounds__(256) void cvt_kernel(const float* __restrict__ in,
                                                  short* __restrict__ out)
{
  const size_t i = ((size_t)blockIdx.x * 256 + threadIdx.x) * 4;
  const float4 v = *(const float4*)(in + i);
  s16x4 o = { f2bf(v.x), f2bf(v.y), f2bf(v.z), f2bf(v.w) };
  *(s16x4*)(out + i) = o;
}

// ---------------------------------------------------------------------------
// Merged weight conversions + rope table:
// blocks [0,4096) wq; [4096,5120) wk; [5120,6144) wv; [6144,6656) rope tab.
// ---------------------------------------------------------------------------
__global__ __launch_bounds__(256) void wcvt_kernel(
    const float* __restrict__ wq, const float* __restrict__ wk,
    const float* __restrict__ wv, short* __restrict__ wqb,
    short* __restrict__ wkb, short* __restrict__ wvb,
    float2* __restrict__ tab)
{
  const int bid = blockIdx.x;
  if (bid < 6144) {
    const float* in; short* out; int lb;
    if (bid < 4096)      { in = wq; out = wqb; lb = bid; }
    else if (bid < 5120) { in = wk; out = wkb; lb = bid - 4096; }
    else                 { in = wv; out = wvb; lb = bid - 5120; }
    const size_t i = ((size_t)lb * 256 + threadIdx.x) * 4;
    const float4 v = *(const float4*)(in + i);
    s16x4 o = { f2bf(v.x), f2bf(v.y), f2bf(v.z), f2bf(v.w) };
    *(s16x4*)(out + i) = o;
  } else {
    const int i = (bid - 6144) * 256 + threadIdx.x;   // 131072
    const int d = i & 63;
    const float fr = (float)(i >> 6) * exp2f((float)d * -0.20762050593048584f);
    float sn, cs;
    sincosf(fr, &sn, &cs);
    tab[i] = make_float2(cs, sn);
  }
}

// ---------------------------------------------------------------------------
// GEMM (small-N): C[M,N] = A[M,K] * W[N,K]^T + bias[N]. 128x128 tile, BK=64,
// 256 threads. omode: 0 = bf16 C row-major; 1 = fp32 C row-major;
// 3 = split KV. XCD remap for grid 8x64 (KV call).
// ---------------------------------------------------------------------------
__global__ __launch_bounds__(256) void gemm_bt(
    const short* __restrict__ A, const short* __restrict__ W,
    const float* __restrict__ bias, const float* __restrict__ bias2,
    void* __restrict__ C, void* __restrict__ C2,
    int M, int N, int K, int omode)
{
  __shared__ __align__(16) short As[128 * 64];
  __shared__ __align__(16) short Bs[128 * 64];

  const int t = threadIdx.x;
  const int l = t & 63;
  const int w = t >> 6;
  const int lane16 = l & 15;
  const int quad = l >> 4;
  const int wm = w >> 1, wn = w & 1;

  int bx = blockIdx.x, by = blockIdx.y;
  if (gridDim.x == 8 && gridDim.y == 64) {       // KV call: XCD-aware remap
    const int lid = blockIdx.x + 8 * blockIdx.y;
    const int xcd = lid & 7, idx = lid >> 3;
    by = xcd * 8 + (idx >> 3);
    bx = idx & 7;
  }
  const int mb0 = by * 128;
  const int nb0 = bx * 128;

  const f32x4 zero = {0.f, 0.f, 0.f, 0.f};
  f32x4 acc[4][4];
#pragma unroll
  for (int i = 0; i < 4; ++i)
#pragma unroll
    for (int j = 0; j < 4; ++j) acc[i][j] = zero;

  const int sr = t >> 3;
  const int sp = t & 7;
  const short* Ag = A + (size_t)(mb0 + sr) * K + sp * 8;
  const short* Wg = W + (size_t)(nb0 + sr) * K + sp * 8;
  short* Al = As + t * 8;
  short* Bl = Bs + t * 8;

  const int nkt = K >> 6;
  for (int kt = 0; kt < nkt; ++kt) {
    __syncthreads();
    const int kof = kt * 64;
#pragma unroll
    for (int it = 0; it < 4; ++it) {
      GLOAD_LDS16(Ag + kof + (size_t)(it * 32) * K, Al + it * 2048);
      GLOAD_LDS16(Wg + kof + (size_t)(it * 32) * K, Bl + it * 2048);
    }
    __syncthreads();
#pragma unroll
    for (int kk = 0; kk < 2; ++kk) {
      s16x8 af[4], bf[4];
#pragma unroll
      for (int mi = 0; mi < 4; ++mi)
        af[mi] = *(const s16x8*)&As[(wm * 64 + mi * 16 + lane16) * 64 +
                                    kk * 32 + quad * 8];
#pragma unroll
      for (int ni = 0; ni < 4; ++ni)
        bf[ni] = *(const s16x8*)&Bs[(wn * 64 + ni * 16 + lane16) * 64 +
                                    kk * 32 + quad * 8];
#pragma unroll
      for (int mi = 0; mi < 4; ++mi)
#pragma unroll
        for (int ni = 0; ni < 4; ++ni)
          acc[mi][ni] = __builtin_amdgcn_mfma_f32_16x16x32_bf16(
              af[mi], bf[ni], acc[mi][ni], 0, 0, 0);
    }
  }

#pragma unroll
  for (int ni = 0; ni < 4; ++ni) {
    const int n = nb0 + wn * 64 + ni * 16 + lane16;
    const float bvx = (omode == 3 && n >= 512) ? bias2[n - 512] : bias[n];
#pragma unroll
    for (int mi = 0; mi < 4; ++mi) {
      const int m0 = mb0 + wm * 64 + mi * 16 + quad * 4;
#pragma unroll
      for (int r = 0; r < 4; ++r) {
        const int m = m0 + r;
        const float v = acc[mi][ni][r] + bvx;
        if (omode == 0) {
          ((short*)C)[(size_t)m * N + n] = f2bf(v);
        } else if (omode == 1) {
          ((float*)C)[(size_t)m * N + n] = v;
        } else {
          if (n < 512) ((short*)C)[(size_t)m * 512 + n] = f2bf(v);
          else         ((short*)C2)[(size_t)m * 512 + (n - 512)] = f2bf(v);
        }
      }
    }
  }
}

// ---------------------------------------------------------------------------
// GEMM (big): 256x256 tile, BK=64, 512 threads = 8 waves (2M x 4N), 8-phase
// schedule (T2+T3+T4+T5), counted vmcnt(6) at P4/P8 only (r7 ledger).
// XCD remap for grid 8x32. omode: 0 = bf16 C; 1 = fp32 C.
// ---------------------------------------------------------------------------
__global__ __launch_bounds__(512, 2) void gemm256_bt(
    const short* __restrict__ A, const short* __restrict__ W,
    const float* __restrict__ bias, void* __restrict__ C,
    int M, int N, int K, int omode)
{
  __shared__ __align__(16) short Asm[2 * 16384];   // [buf][kk][row][32]
  __shared__ __align__(16) short Bsm[2 * 16384];

  const int t = threadIdx.x;
  const int l = t & 63;
  const int w = t >> 6;
  const int lane16 = l & 15;
  const int quad = l >> 4;
  const int wm = w >> 2;
  const int wn = w & 3;

  int bx = blockIdx.x, by = blockIdx.y;
  if (gridDim.x == 8 && gridDim.y == 32) {
    const int bid = blockIdx.y * 8 + blockIdx.x;
    const int xcd = bid & 7, idx = bid >> 3;
    const int xc = xcd & 3, yc = xcd >> 2;
    bx = xc * 2 + (idx & 1);
    by = yc * 16 + (idx >> 1);
  }
  const int mb0 = by * 256;
  const int nb0 = bx * 256;

  const f32x4 zero = {0.f, 0.f, 0.f, 0.f};
  f32x4 acc[8][4];
#pragma unroll
  for (int i = 0; i < 8; ++i)
#pragma unroll
    for (int j = 0; j < 4; ++j) acc[i][j] = zero;

  const int srow = t >> 2;
  const int scs = (t & 3) ^ ((t >> 3) & 3);
  const short* Ag = A + (size_t)(mb0 + srow) * K + scs * 8;
  const short* Wg = W + (size_t)(nb0 + srow) * K + scs * 8;
  const size_t rstep = (size_t)128 * K;

#define STAGE_A(b, kt, kh)                                                    \
  do {                                                                        \
    const size_t ko_ = (size_t)(kt) * 64 + (kh) * 32;                         \
    GLOAD_LDS16(Ag + ko_,         Asm + (b) * 16384 + (kh) * 8192 + t * 8);   \
    GLOAD_LDS16(Ag + ko_ + rstep, Asm + (b) * 16384 + (kh) * 8192 + 4096 + t * 8); \
  } while (0)
#define STAGE_B(b, kt, kh)                                                    \
  do {                                                                        \
    const size_t ko_ = (size_t)(kt) * 64 + (kh) * 32;                         \
    GLOAD_LDS16(Wg + ko_,         Bsm + (b) * 16384 + (kh) * 8192 + t * 8);   \
    GLOAD_LDS16(Wg + ko_ + rstep, Bsm + (b) * 16384 + (kh) * 8192 + 4096 + t * 8); \
  } while (0)

#define VMW6                                                                  \
  asm volatile("s_waitcnt vmcnt(6)" ::: "memory");                            \
  __builtin_amdgcn_sched_barrier(0);

  s16x8 bfr[4];

#define DO_PHASE(BUF, KK, MG, READB, STAGE_STMT, VM_STMT)                     \
  {                                                                           \
    const short* Abase = Asm + (BUF) * 16384 + (KK) * 8192;                   \
    const short* Bbase = Bsm + (BUF) * 16384 + (KK) * 8192;                   \
    if (READB) {                                                              \
      _Pragma("unroll")                                                       \
      for (int ni = 0; ni < 4; ++ni) {                                        \
        const int nr = wn * 64 + ni * 16 + lane16;                            \
        bfr[ni] = *(const s16x8*)(Bbase + nr * 32 +                           \
                                  ((quad ^ ((nr >> 1) & 3)) << 3));           \
      }                                                                       \
    }                                                                         \
    s16x8 afr[4];                                                             \
    _Pragma("unroll")                                                         \
    for (int mi2 = 0; mi2 < 4; ++mi2) {                                       \
      const int mr = wm * 128 + (MG) * 64 + mi2 * 16 + lane16;                \
      afr[mi2] = *(const s16x8*)(Abase + mr * 32 +                            \
                                 ((quad ^ ((mr >> 1) & 3)) << 3));            \
    }                                                                         \
    STAGE_STMT;                                                               \
    __builtin_amdgcn_s_barrier();                                             \
    asm volatile("s_waitcnt lgkmcnt(0)" ::: "memory");                        \
    __builtin_amdgcn_sched_barrier(0);                                        \
    __builtin_amdgcn_s_setprio(1);                                            \
    _Pragma("unroll")                                                         \
    for (int mi2 = 0; mi2 < 4; ++mi2)                                         \
      _Pragma("unroll")                                                       \
      for (int ni = 0; ni < 4; ++ni)                                          \
        acc[(MG) * 4 + mi2][ni] = __builtin_amdgcn_mfma_f32_16x16x32_bf16(    \
            afr[mi2], bfr[ni], acc[(MG) * 4 + mi2][ni], 0, 0, 0);             \
    __builtin_amdgcn_s_setprio(0);                                            \
    VM_STMT                                                                   \
    __builtin_amdgcn_s_barrier();                                             \
  }

  const int NT = K >> 6;

  STAGE_B(0, 0, 0); STAGE_A(0, 0, 0); STAGE_B(0, 0, 1); STAGE_A(0, 0, 1);
  STAGE_B(1, 1, 0); STAGE_A(1, 1, 0); STAGE_B(1, 1, 1);
  asm volatile("s_waitcnt vmcnt(6)" ::: "memory");
  __builtin_amdgcn_sched_barrier(0);
  __builtin_amdgcn_s_barrier();

  for (int i2 = 0; i2 < NT; i2 += 2) {
    const int tp1 = (i2 + 1 < NT) ? i2 + 1 : NT - 1;
    const int tp2 = (i2 + 2 < NT) ? i2 + 2 : NT - 1;
    const int tp3 = (i2 + 3 < NT) ? i2 + 3 : NT - 1;
    DO_PHASE(0, 0, 0, true,  STAGE_A(1, tp1, 1), )        // P1
    DO_PHASE(0, 0, 1, false, STAGE_B(0, tp2, 0), )        // P2
    DO_PHASE(0, 1, 0, true,  STAGE_A(0, tp2, 0), )        // P3
    DO_PHASE(0, 1, 1, false, STAGE_B(0, tp2, 1), VMW6)    // P4
    DO_PHASE(1, 0, 0, true,  STAGE_A(0, tp2, 1), )        // P5
    DO_PHASE(1, 0, 1, false, STAGE_B(1, tp3, 0), )        // P6
    DO_PHASE(1, 1, 0, true,  STAGE_A(1, tp3, 0), )        // P7
    DO_PHASE(1, 1, 1, false, STAGE_B(1, tp3, 1), VMW6)    // P8
  }

#pragma unroll
  for (int ni = 0; ni < 4; ++ni) {
    const int n = nb0 + wn * 64 + ni * 16 + lane16;
    const float bv = bias[n];
#pragma unroll
    for (int mi = 0; mi < 8; ++mi) {
      const int m0 = mb0 + wm * 128 + mi * 16 + quad * 4;
#pragma unroll
      for (int r = 0; r < 4; ++r) {
        const float v = acc[mi][ni][r] + bv;
        if (omode == 0) ((short*)C)[(size_t)(m0 + r) * N + n] = f2bf(v);
        else            ((float*)C)[(size_t)(m0 + r) * N + n] = v;
      }
    }
  }
#undef DO_PHASE
#undef STAGE_A
#undef STAGE_B
#undef VMW6
}

// ---------------------------------------------------------------------------
// RoPE in place on bf16 buf[row][head*128 + d] (K only; Q fused in attn).
// ---------------------------------------------------------------------------
__global__ __launch_bounds__(256) void rope_kernel(short* __restrict__ buf,
                                                   int lognh,
                                                   const float2* __restrict__ tab)
{
  const int idx = blockIdx.x * 256 + threadIdx.x;
  const int d = idx & 63;
  const int rest = idx >> 6;
  const int row = rest >> lognh;
  const int pos = row & 2047;
  const float2 cssn = tab[(pos << 6) | d];
  const float cs = cssn.x, sn = cssn.y;
  const size_t base = (size_t)rest * 128 + d;
  const float lo = bf2f(buf[base]);
  const float hi = bf2f(buf[base + 64]);
  buf[base]      = f2bf(lo * cs - hi * sn);
  buf[base + 64] = f2bf(hi * cs + lo * sn);
}

// ---------------------------------------------------------------------------
// Transpose V: in[m=b*2048+s][n(512)] -> out[(b*512+n)*2048 + s].
// ---------------------------------------------------------------------------
__global__ __launch_bounds__(256) void trans_kernel(const short* __restrict__ in,
                                                    short* __restrict__ out)
{
  __shared__ short T[64 * 72];
  const int t = threadIdx.x;
  const int ms = blockIdx.x * 64;
  const int ns = blockIdx.y * 64;
  const int b = ms >> 11;
  const int sl = ms & 2047;
  const int r = t >> 3, sg = t & 7;
#pragma unroll
  for (int j = 0; j < 2; ++j) {
    const uint4 v = *(const uint4*)(in + (size_t)(ms + r + 32 * j) * 512 + ns + sg * 8);
    *(uint4*)&T[(r + 32 * j) * 72 + sg * 8] = v;
  }
  __syncthreads();
#pragma unroll
  for (int j = 0; j < 2; ++j) {
    const int nr = r + 32 * j;
    s16x8 v;
#pragma unroll
    for (int i = 0; i < 8; ++i) v[i] = T[(sg * 8 + i) * 72 + nr];
    *(s16x8*)(out + ((size_t)(b * 512 + ns + nr)) * 2048 + sl + sg * 8) = v;
  }
}

// ---------------------------------------------------------------------------
// Flash attention, causal, GQA. r11: OCCUPANCY version. r10's 32x32 swapped
// math, but K and V SINGLE-buffered (LDS 64->32 KB) so 4 blocks/CU fit
// (VGPR 116 -> 4 waves/SIMD permitted; LDS was the limiter), and grid split
// to 1024 one-strip blocks so 4 are actually resident -> cross-block phase
// diversity lets MFMA and VALU pipes dual-issue (m114) instead of the
// barrier-locked alternation that pinned r7-r10 at ~140us.
// 2-barrier/tile schedule (r6 measured 1-vs-2 barriers neutral):
//   [K(t),V(t) staged]  QK -> barA -> K-DMA(t+1) -> softmax+PV -> barB ->
//   V-DMA(t+1).  Drains: K(t+1) flies under softmax+PV, drained at barB
//   (before QK(t+1)); V(t+1) drained at barA(t+1) (before PV(t+1)).
// In-place og==qg safe (block reads only its own Q rows before storing them).
// ---------------------------------------------------------------------------
__global__ __launch_bounds__(256, 2) void attn_kernel(
    const short* __restrict__ qg, const short* __restrict__ kg,
    const short* __restrict__ vtg, short* __restrict__ og,
    const float2* __restrict__ tab)
{
  __shared__ __align__(16) short Ksm[64 * 128];   // [key][d], swz c^row&15
  __shared__ __align__(16) short Vsm[128 * 64];   // [d][key], swz c^row&7

  const int t = threadIdx.x;
  const int l = t & 63;
  const int w = t >> 6;                 // 0..3
  const int l31 = l & 31;
  const int h2 = l >> 5;                // half: 0/1

  // XCD remap: 1024 blocks; xcd gets 128 = 2 whole (b,kv) groups (K/V panels
  // L2-resident per XCD). Within group: h = kv*4 + (wv>>4), jj = wv&15.
  const int lid = blockIdx.x + 16 * (blockIdx.y + 16 * blockIdx.z);
  const int xcd = lid & 7, idx = lid >> 3;        // idx 0..127
  const int g = xcd * 2 + (idx >> 6);             // 0..15
  const int wv_ = idx & 63;
  const int b = g >> 2, kv = g & 3;
  const int h = kv * 4 + (wv_ >> 4);
  const int jj = wv_ & 15;

  // DMA staging (256 threads, 4 issues each, 16B/lane, linear LDS dest t*16):
  // K 64x128: issue j rows j*16+(t>>4); src seg = (t&15) ^ (row&15 = t>>4).
  // V 128x64: issue j rows j*32+(t>>3); src seg = (t&7) ^ ((t>>3)&7).
  const int krow0 = t >> 4, kseg = (t & 15) ^ (t >> 4);
  const int vrow0 = t >> 3, vseg = (t & 7) ^ ((t >> 3) & 7);

  const short* kbaseptr = kg + ((size_t)(b * 2048)) * 512 + kv * 128;
  const short* vbaseptr = vtg + ((size_t)(b * 512 + kv * 128)) * 2048;

  const float SC = 0.08838834764831845f * 1.4426950408889634f; // rsqrt(128)*log2e
  const f32x16 zero16 = {0.f,0.f,0.f,0.f,0.f,0.f,0.f,0.f,
                         0.f,0.f,0.f,0.f,0.f,0.f,0.f,0.f};

#define STAGE_K()                                                             \
  do {                                                                        \
    GLOAD_LDS16(ksrc,          Ksm + t * 8);                                  \
    GLOAD_LDS16(ksrc + 8192,   Ksm + 2048 + t * 8);                           \
    GLOAD_LDS16(ksrc + 16384,  Ksm + 4096 + t * 8);                           \
    GLOAD_LDS16(ksrc + 24576,  Ksm + 6144 + t * 8);                           \
    ksrc += 64 * 512;                                                         \
  } while (0)
#define STAGE_V()                                                             \
  do {                                                                        \
    GLOAD_LDS16(vsrc,          Vsm + t * 8);                                  \
    GLOAD_LDS16(vsrc + 65536,  Vsm + 2048 + t * 8);                           \
    GLOAD_LDS16(vsrc + 131072, Vsm + 4096 + t * 8);                           \
    GLOAD_LDS16(vsrc + 196608, Vsm + 6144 + t * 8);                           \
    vsrc += 64;                                                               \
  } while (0)

  const int qb0 = jj * 128;
  const int qw0 = qb0 + w * 32;         // wave owns 32 q rows
  const int qmaxw = qw0 + 31;
  const int ntl = 2 * jj + 2;

  const short* ksrc = kbaseptr + (size_t)krow0 * 512 + kseg * 8;
  const short* vsrc = vbaseptr + (size_t)vrow0 * 2048 + vseg * 8;

  // Q B-frags with FUSED RoPE: lane holds Q[q=qw0+l31][d=16m+8*h2+j], m 0..7.
  // RoPE pairs (d, d+64) = (qf[m], qf[m+4]); angle index d_lo = 16m+8h2+j.
  s16x8 qf[8];
  {
    const int pos = qw0 + l31;
    const short* qrow =
        qg + ((size_t)(b * 2048 + pos)) * 2048 + h * 128 + 8 * h2;
    s16x8 qr[8];
#pragma unroll
    for (int m = 0; m < 8; ++m) qr[m] = *(const s16x8*)(qrow + 16 * m);
    const float2* tb = tab + (((size_t)pos) << 6) + 8 * h2;
#pragma unroll
    for (int m = 0; m < 4; ++m) {
      float lo[8], hi[8];
#pragma unroll
      for (int j = 0; j < 8; ++j) {
        const float2 cs2 = tb[16 * m + j];
        const float l0 = bf2f(qr[m][j]);
        const float h0 = bf2f(qr[m + 4][j]);
        lo[j] = l0 * cs2.x - h0 * cs2.y;
        hi[j] = h0 * cs2.x + l0 * cs2.y;
      }
      union { unsigned int u[4]; s16x8 v; } plo, phi;
#pragma unroll
      for (int j = 0; j < 4; ++j) {
        asm("v_cvt_pk_bf16_f32 %0, %1, %2"
            : "=v"(plo.u[j]) : "v"(lo[2 * j]), "v"(lo[2 * j + 1]));
        asm("v_cvt_pk_bf16_f32 %0, %1, %2"
            : "=v"(phi.u[j]) : "v"(hi[2 * j]), "v"(hi[2 * j + 1]));
      }
      qf[m] = plo.v;
      qf[m + 4] = phi.v;
    }
  }

  f32x16 o32[4];
#pragma unroll
  for (int nb = 0; nb < 4; ++nb) o32[nb] = zero16;
  float m_i = NEGH, l_i = 0.f;        // per-lane stats for q = qw0 + l31

  // prologue: stage tile 0 (pointers advance to tile 1)
  STAGE_K();
  STAGE_V();
  __syncthreads();

  for (int tl = 0; tl < ntl; ++tl) {
    const int kbase = tl * 64;
    const bool cmp = (kbase <= qmaxw);

    f32x16 st0 = zero16, st1 = zero16;
    if (cmp) {
      // QK: C col=q=l31, row(reg)=(reg&3)+8*(reg>>2)+4*h2 (key within block)
      __builtin_amdgcn_s_setprio(1);
#pragma unroll
      for (int m = 0; m < 8; ++m) {
        const int ch = ((2 * m + h2) ^ (l & 15)) * 8;
        const s16x8 a0 = *(const s16x8*)&Ksm[l31 * 128 + ch];
        const s16x8 a1 = *(const s16x8*)&Ksm[(32 + l31) * 128 + ch];
        st0 = __builtin_amdgcn_mfma_f32_32x32x16_bf16(a0, qf[m], st0, 0, 0, 0);
        st1 = __builtin_amdgcn_mfma_f32_32x32x16_bf16(a1, qf[m], st1, 0, 0, 0);
      }
      __builtin_amdgcn_s_setprio(0);
    }

    __syncthreads();                    // barA: QK readers done; V(t) drained
    if (tl + 1 < ntl) STAGE_K();        // overwrite Ksm with K(t+1); flies
                                        // under softmax+PV, drained at barB

    if (cmp) {
      // causal mask (raw scores; SC folded into exp2)
      const bool maskt = (kbase + 63 > qw0);
      const int qabs = qw0 + l31;
      if (maskt) {
#pragma unroll
        for (int r = 0; r < 16; ++r) {
          const int krow = (r & 3) + 8 * (r >> 2) + 4 * h2;
          if (kbase + krow > qabs) st0[r] = NEGH;
          if (kbase + 32 + krow > qabs) st1[r] = NEGH;
        }
      }
      float tm = NEGH;
#pragma unroll
      for (int r = 0; r < 16; ++r) tm = fmaxf(tm, fmaxf(st0[r], st1[r]));
      float tl_ = fmaxf(tm, __shfl_xor(tm, 32));
      const float mnew = fmaxf(m_i, tl_);
      if (!__all(tl_ <= m_i)) {         // exact skip: alpha==1 when max static
        const float alpha = exp2f((m_i - mnew) * SC);
        l_i *= alpha;
#pragma unroll
        for (int r = 0; r < 16; ++r) {
          const int qrow = (r & 3) + 8 * (r >> 2) + 4 * h2;
          const float ar = __shfl(alpha, qrow);
#pragma unroll
          for (int nb = 0; nb < 4; ++nb) o32[nb][r] *= ar;
        }
      }
      m_i = mnew;
      const float mS = mnew * SC;
      float rs = 0.f;
#pragma unroll
      for (int r = 0; r < 16; ++r) {
        st0[r] = exp2f(fmaf(st0[r], SC, -mS));
        st1[r] = exp2f(fmaf(st1[r], SC, -mS));
        rs += st0[r] + st1[r];
      }
      rs += __shfl_xor(rs, 32);
      l_i += rs;

      // pack P->bf16: W[g] (g=key>>2): g = 2a + h2 + 8kb; a = reg>>2.
      unsigned int wA[8], wB[8];
#pragma unroll
      for (int a = 0; a < 4; ++a) {
        asm("v_cvt_pk_bf16_f32 %0, %1, %2"
            : "=v"(wA[a]) : "v"(st0[4 * a]), "v"(st0[4 * a + 1]));
        asm("v_cvt_pk_bf16_f32 %0, %1, %2"
            : "=v"(wB[a]) : "v"(st0[4 * a + 2]), "v"(st0[4 * a + 3]));
        asm("v_cvt_pk_bf16_f32 %0, %1, %2"
            : "=v"(wA[a + 4]) : "v"(st1[4 * a]), "v"(st1[4 * a + 1]));
        asm("v_cvt_pk_bf16_f32 %0, %1, %2"
            : "=v"(wB[a + 4]) : "v"(st1[4 * a + 2]), "v"(st1[4 * a + 3]));
      }

      // PV: per kk (16-key slice): A-frag keys 16kk+8*h2+0..7 = groups
      // ga=4kk+2h2, gb=ga+1. h2=0 sends wX[i0+1], h2=1 sends wX[i0];
      // i0 = 2*(kk&1)+4*(kk>>1). frag(h2=0)=[own(i0),recv];
      // frag(h2=1)=[recv,own(i0+1)].
      __builtin_amdgcn_s_setprio(1);
#pragma unroll
      for (int kk = 0; kk < 4; ++kk) {
        const int i0 = 2 * (kk & 1) + 4 * (kk >> 1);
        const unsigned int sA = h2 ? wA[i0] : wA[i0 + 1];
        const unsigned int sB = h2 ? wB[i0] : wB[i0 + 1];
        const unsigned int rA = (unsigned int)__shfl_xor((int)sA, 32);
        const unsigned int rB = (unsigned int)__shfl_xor((int)sB, 32);
        union { unsigned int u[4]; s16x8 v; } pfu;
        pfu.u[0] = h2 ? rA : wA[i0];
        pfu.u[1] = h2 ? rB : wB[i0];
        pfu.u[2] = h2 ? wA[i0 + 1] : rA;
        pfu.u[3] = h2 ? wB[i0 + 1] : rB;
        const s16x8 pf = pfu.v;
#pragma unroll
        for (int nb = 0; nb < 4; ++nb) {
          const s16x8 vf = *(const s16x8*)&Vsm[(nb * 32 + l31) * 64 +
                                               (((2 * kk + h2) ^ (l & 7)) * 8)];
          o32[nb] = __builtin_amdgcn_mfma_f32_32x32x16_bf16(pf, vf, o32[nb],
                                                            0, 0, 0);
        }
      }
      __builtin_amdgcn_s_setprio(0);
    }

    __syncthreads();                    // barB: PV readers done; K(t+1) drained
    if (tl + 1 < ntl) STAGE_V();        // overwrite Vsm with V(t+1); drained
                                        // at next barA before PV reads it
  }

  // store: O C-layout col=d=nb*32+l31, row(reg)=qrow; coalesced 64B runs.
#pragma unroll
  for (int r = 0; r < 16; ++r) {
    const int qrow = (r & 3) + 8 * (r >> 2) + 4 * h2;
    const float lr = __shfl(l_i, qrow);
    const float inv = 1.f / lr;
    const size_t base =
        ((size_t)(b * 2048 + qw0 + qrow)) * 2048 + h * 128 + l31;
#pragma unroll
    for (int nb = 0; nb < 4; ++nb)
      og[base + nb * 32] = f2bf(o32[nb][r] * inv);
  }
#undef STAGE_K
#undef STAGE_V
}

// ---------------------------------------------------------------------------
extern "C" void kernel_launch(void* const* d_in, const int* in_sizes, int n_in,
                              void* d_out, int out_size, void* d_ws,
                              size_t ws_size, hipStream_t stream)
{
  const float* x  = (const float*)d_in[0];
  const float* wq = (const float*)d_in[1];
  const float* bq = (const float*)d_in[2];
  const float* wk = (const float*)d_in[3];
  const float* bk = (const float*)d_in[4];
  const float* wv = (const float*)d_in[5];
  const float* bv = (const float*)d_in[6];
  const float* wo = (const float*)d_in[7];
  const float* bo = (const float*)d_in[8];
  float* out = (float*)d_out;

  // ws layout (77 MiB used; ws_size >= 80 MiB):
  //   xb  @0      32 MiB  [8192][2048] bf16; dead after KV-proj -> wob reuses @0
  //   wqb @32MiB   8 MiB; wkb @40MiB 2 MiB; wvb @42MiB 2 MiB
  //   qws @44MiB  32 MiB  [8192][2048] bf16; attention output in place
  //   tab @76MiB   1 MiB  float2[2048][64] rope cos/sin
  // d_out scratch: kws @out+0 8 MiB; vtw @out+8M 8 MiB; vtmp @out+16M 8 MiB
  char* ws = (char*)d_ws;
  short* xb  = (short*)ws;
  short* wqb = (short*)(ws + (32ull << 20));
  short* wkb = (short*)(ws + (40ull << 20));
  short* wvb = (short*)(ws + (42ull << 20));
  short* qws = (short*)(ws + (44ull << 20));
  float2* tab = (float2*)(ws + (76ull << 20));
  short* wob = xb;
  short* kws = (short*)d_out;
  short* vtw = (short*)((char*)d_out + (8ull << 20));
  short* vtmp = (short*)((char*)d_out + (16ull << 20));

  const dim3 blk(256);
  cvt_kernel<<<16384, blk, 0, stream>>>(x, xb);
  wcvt_kernel<<<6656, blk, 0, stream>>>(wq, wk, wv, wqb, wkb, wvb, tab);
  gemm256_bt<<<dim3(8, 32), dim3(512), 0, stream>>>(xb, wqb, bq, qws, 8192, 2048, 2048, 0);
  gemm_bt<<<dim3(8, 64), blk, 0, stream>>>(xb, wkb, bk, bv, kws, vtmp, 8192, 1024, 2048, 3);
  trans_kernel<<<dim3(128, 8), blk, 0, stream>>>(vtmp, vtw);
  rope_kernel<<<8192, blk, 0, stream>>>(kws, 2, tab);   // K only; Q-rope fused
  cvt_kernel<<<4096, blk, 0, stream>>>(wo, wob);        // after KV-proj (xb dead)
  attn_kernel<<<dim3(16, 16, 4), blk, 0, stream>>>(qws, kws, vtw, qws, tab);
  gemm256_bt<<<dim3(8, 32), dim3(512), 0, stream>>>(qws, wob, bo, out, 8192, 2048, 2048, 1);
}